// Round 1
// baseline (108.266 us; speedup 1.0000x reference)
//
#include <hip/hip_runtime.h>

constexpr int NL = 32;    // layers
constexpr int PPT = 4;    // points per thread

__device__ __forceinline__ float fast_tanh(float x) {
    // tanh(x) = 1 - 2/(e^{2x}+1); saturates correctly for large |x|
    float e = __expf(2.0f * x);
    float r = __builtin_amdgcn_rcpf(e + 1.0f);
    return fmaf(-2.0f, r, 1.0f);
}

__global__ __launch_bounds__(256) void sympnet_kernel(
    const float* __restrict__ x,
    const float* __restrict__ act_w,
    const float* __restrict__ bias_b,
    const float* __restrict__ lin_w,
    float* __restrict__ out,
    int nthreads_total)
{
    // Per-layer folded affine tables:
    // sf[i] = { m00,m01,m10,m11, c0=(M·b).x, c1=(M·b).y, act_w, pad }   (forward)
    // si[i] = { m11,-m01,-m10,m00, -b0, -b1, act_w, pad }               (inverse)
    __shared__ float sf[NL][8];
    __shared__ float si[NL][8];

    int t = threadIdx.x;
    if (t < NL) {
        // Compose the 8 unit shears of layer t into a 2x2 matrix (det = 1).
        float m00 = 1.f, m01 = 0.f, m10 = 0.f, m11 = 1.f;
        #pragma unroll
        for (int j = 0; j < 8; ++j) {
            float w = lin_w[t * 8 + j];
            if ((j & 1) == 0) { // q += w*p : row0 += w*row1
                m00 = fmaf(w, m10, m00); m01 = fmaf(w, m11, m01);
            } else {            // p += w*q : row1 += w*row0
                m10 = fmaf(w, m00, m10); m11 = fmaf(w, m01, m11);
            }
        }
        float b0 = bias_b[2 * t], b1 = bias_b[2 * t + 1];
        float aw = act_w[t];
        sf[t][0] = m00; sf[t][1] = m01; sf[t][2] = m10; sf[t][3] = m11;
        sf[t][4] = fmaf(m00, b0, m01 * b1);   // (M·b).x
        sf[t][5] = fmaf(m10, b0, m11 * b1);   // (M·b).y
        sf[t][6] = aw; sf[t][7] = 0.f;
        si[t][0] = m11; si[t][1] = -m01; si[t][2] = -m10; si[t][3] = m00;
        si[t][4] = -b0; si[t][5] = -b1; si[t][6] = aw; si[t][7] = 0.f;
    }
    __syncthreads();

    int gid = blockIdx.x * blockDim.x + t;
    if (gid >= nthreads_total) return;

    const float4* x4 = (const float4*)x;
    float4 v0 = x4[2 * gid];
    float4 v1 = x4[2 * gid + 1];
    float q[PPT] = {v0.x, v0.z, v1.x, v1.z};
    float p[PPT] = {v0.y, v0.w, v1.y, v1.w};

    // ---------------- forward chain ----------------
    #pragma unroll 1
    for (int i = 0; i < NL; i += 2) {
        // layer i (even): q += aw*tanh(p), then v <- M*(v+b) = M*v + c
        float4 M = *(const float4*)&sf[i][0];
        float4 C = *(const float4*)&sf[i][4];   // c0, c1, aw, pad
        #pragma unroll
        for (int k = 0; k < PPT; ++k) {
            float qq = fmaf(C.z, fast_tanh(p[k]), q[k]);
            float nq = fmaf(M.y, p[k], C.x); nq = fmaf(M.x, qq, nq);
            float np = fmaf(M.w, p[k], C.y); np = fmaf(M.z, qq, np);
            q[k] = nq; p[k] = np;
        }
        // layer i+1 (odd): p += aw*tanh(q), then affine
        float4 M2 = *(const float4*)&sf[i + 1][0];
        float4 C2 = *(const float4*)&sf[i + 1][4];
        #pragma unroll
        for (int k = 0; k < PPT; ++k) {
            float pp = fmaf(C2.z, fast_tanh(q[k]), p[k]);
            float nq = fmaf(M2.y, pp, C2.x); nq = fmaf(M2.x, q[k], nq);
            float np = fmaf(M2.w, pp, C2.y); np = fmaf(M2.z, q[k], np);
            q[k] = nq; p[k] = np;
        }
    }

    // time reversal
    #pragma unroll
    for (int k = 0; k < PPT; ++k) p[k] = -p[k];

    // ---------------- inverse chain ----------------
    #pragma unroll 1
    for (int i = NL - 1; i >= 0; i -= 2) {
        // layer i (odd): v <- Minv*v - b, then p -= aw*tanh(q)
        float4 M = *(const float4*)&si[i][0];
        float4 C = *(const float4*)&si[i][4];   // -b0, -b1, aw, pad
        #pragma unroll
        for (int k = 0; k < PPT; ++k) {
            float nq = fmaf(M.x, q[k], C.x); nq = fmaf(M.y, p[k], nq);
            float np = fmaf(M.z, q[k], C.y); np = fmaf(M.w, p[k], np);
            np = fmaf(-C.z, fast_tanh(nq), np);
            q[k] = nq; p[k] = np;
        }
        // layer i-1 (even): affine-inv, then q -= aw*tanh(p)
        float4 M2 = *(const float4*)&si[i - 1][0];
        float4 C2 = *(const float4*)&si[i - 1][4];
        #pragma unroll
        for (int k = 0; k < PPT; ++k) {
            float nq = fmaf(M2.x, q[k], C2.x); nq = fmaf(M2.y, p[k], nq);
            float np = fmaf(M2.z, q[k], C2.y); np = fmaf(M2.w, p[k], np);
            nq = fmaf(-C2.z, fast_tanh(np), nq);
            q[k] = nq; p[k] = np;
        }
    }

    // final scale [1, -1]
    float4 o0 = {q[0], -p[0], q[1], -p[1]};
    float4 o1 = {q[2], -p[2], q[3], -p[3]};
    float4* out4 = (float4*)out;
    out4[2 * gid] = o0;
    out4[2 * gid + 1] = o1;
}

extern "C" void kernel_launch(void* const* d_in, const int* in_sizes, int n_in,
                              void* d_out, int out_size, void* d_ws, size_t ws_size,
                              hipStream_t stream) {
    const float* x      = (const float*)d_in[0];
    const float* act_w  = (const float*)d_in[1];
    const float* bias_b = (const float*)d_in[2];
    const float* lin_w  = (const float*)d_in[3];
    float* out = (float*)d_out;

    int npts = in_sizes[0] / 2;            // 2097152 points
    int nthreads = npts / PPT;             // 524288 threads
    int blocks = (nthreads + 255) / 256;   // 2048 blocks
    sympnet_kernel<<<blocks, 256, 0, stream>>>(x, act_w, bias_b, lin_w, out, nthreads);
}

// Round 2
// 103.989 us; speedup vs baseline: 1.0411x; 1.0411x over previous
//
#include <hip/hip_runtime.h>

constexpr int NL = 32;    // layers
constexpr int PPT = 8;    // points per thread

// State is tracked scaled by c = 2*log2(e) so that e^{2p} = 2^(P) is a bare
// v_exp_f32. All affine table constants are pre-scaled by c in build_tables.
#define C_SCALE 2.8853900817779268f    // 2*log2(e)
#define INV_C   0.34657359027997264f   // ln(2)/2

__device__ __forceinline__ float fast_exp2(float x) {
#if __has_builtin(__builtin_amdgcn_exp2f)
    return __builtin_amdgcn_exp2f(x);
#else
    return __expf(0.69314718055994531f * x);   // fallback: exp(x*ln2)
#endif
}

// Table layout per layer i (16 floats):
//  [0..6]  forward:  m00,m01,m10,m11, C0,C1, T   (T = -2*c*aw; aw-const folded into C)
//  [8..14] inverse:  i00,i01,i10,i11, D0,D1, U   (U = +2*c*aw; -aw-const folded into D)
__global__ void build_tables(const float* __restrict__ act_w,
                             const float* __restrict__ bias_b,
                             const float* __restrict__ lin_w,
                             float* __restrict__ tab)
{
    int t = threadIdx.x;
    if (t >= NL) return;
    // Compose the 8 unit shears into M (det = 1).
    float m00 = 1.f, m01 = 0.f, m10 = 0.f, m11 = 1.f;
    #pragma unroll
    for (int j = 0; j < 8; ++j) {
        float w = lin_w[t * 8 + j];
        if ((j & 1) == 0) { m00 = fmaf(w, m10, m00); m01 = fmaf(w, m11, m01); }
        else              { m10 = fmaf(w, m00, m10); m11 = fmaf(w, m01, m11); }
    }
    float b0 = bias_b[2 * t], b1 = bias_b[2 * t + 1];
    float aw = act_w[t];
    const float c = C_SCALE;
    float awc = aw * c;

    // Forward: activation (tanh add, with +awc folded forward through M), then
    // v <- M*(v + c*b).  C = c*M*b + awc*(M column of the activated coord).
    float C0 = c * fmaf(m00, b0, m01 * b1);
    float C1 = c * fmaf(m10, b0, m11 * b1);
    if ((t & 1) == 0) { C0 = fmaf(awc, m00, C0); C1 = fmaf(awc, m10, C1); } // act on q-row input p
    else              { C0 = fmaf(awc, m01, C0); C1 = fmaf(awc, m11, C1); } // act on p-row input q
    float* f = &tab[t * 16];
    f[0] = m00; f[1] = m01; f[2] = m10; f[3] = m11;
    f[4] = C0;  f[5] = C1;  f[6] = -2.f * awc; f[7] = 0.f;

    // Inverse: v <- Minv*v - c*b, then subtract activation (−awc folded into D).
    float i00 = m11, i01 = -m01, i10 = -m10, i11 = m00;
    float D0 = -c * b0, D1 = -c * b1;
    if ((t & 1) == 0) D0 -= awc; else D1 -= awc;
    f[8]  = i00; f[9]  = i01; f[10] = i10; f[11] = i11;
    f[12] = D0;  f[13] = D1;  f[14] = 2.f * awc; f[15] = 0.f;
}

__global__ __launch_bounds__(256) void sympnet_main(
    const float* __restrict__ x,
    const float* __restrict__ tab,
    float* __restrict__ out)
{
    int gid = blockIdx.x * blockDim.x + threadIdx.x;
    const float4* x4 = (const float4*)x;
    float4* out4 = (float4*)out;
    long base = (long)gid * (PPT / 2);

    float Q[PPT], P[PPT];
    #pragma unroll
    for (int k = 0; k < PPT / 2; ++k) {
        float4 v = x4[base + k];
        Q[2*k]   = C_SCALE * v.x; P[2*k]   = C_SCALE * v.y;
        Q[2*k+1] = C_SCALE * v.z; P[2*k+1] = C_SCALE * v.w;
    }

    // ---------------- forward chain (2 layers / iter) ----------------
    #pragma unroll 1
    for (int i = 0; i < NL; i += 2) {
        const float* f = &tab[i * 16];           // even layer (act on q, tanh(p))
        float m00=f[0], m01=f[1], m10=f[2], m11=f[3], C0=f[4], C1=f[5], T=f[6];
        const float* g = &tab[(i + 1) * 16];     // odd layer (act on p, tanh(q))
        float n00=g[0], n01=g[1], n10=g[2], n11=g[3], E0=g[4], E1=g[5], U=g[6];
        #pragma unroll
        for (int k = 0; k < PPT; ++k) {
            float r  = __builtin_amdgcn_rcpf(fast_exp2(P[k]) + 1.0f);
            float Qa = fmaf(T, r, Q[k]);
            float Qn = fmaf(m00, Qa, fmaf(m01, P[k], C0));
            float Pn = fmaf(m10, Qa, fmaf(m11, P[k], C1));
            float r2 = __builtin_amdgcn_rcpf(fast_exp2(Qn) + 1.0f);
            float Pa = fmaf(U, r2, Pn);
            Q[k] = fmaf(n00, Qn, fmaf(n01, Pa, E0));
            P[k] = fmaf(n10, Qn, fmaf(n11, Pa, E1));
        }
    }

    // time reversal
    #pragma unroll
    for (int k = 0; k < PPT; ++k) P[k] = -P[k];

    // ---------------- inverse chain (2 layers / iter) ----------------
    #pragma unroll 1
    for (int i = NL - 1; i > 0; i -= 2) {
        const float* g = &tab[i * 16 + 8];       // odd layer inverse
        float n00=g[0], n01=g[1], n10=g[2], n11=g[3], E0=g[4], E1=g[5], U=g[6];
        const float* f = &tab[(i - 1) * 16 + 8]; // even layer inverse
        float m00=f[0], m01=f[1], m10=f[2], m11=f[3], C0=f[4], C1=f[5], T=f[6];
        #pragma unroll
        for (int k = 0; k < PPT; ++k) {
            float Qn = fmaf(n00, Q[k], fmaf(n01, P[k], E0));
            float Pn = fmaf(n10, Q[k], fmaf(n11, P[k], E1));
            float r  = __builtin_amdgcn_rcpf(fast_exp2(Qn) + 1.0f);
            Pn = fmaf(U, r, Pn);
            float Q2 = fmaf(m00, Qn, fmaf(m01, Pn, C0));
            float P2 = fmaf(m10, Qn, fmaf(m11, Pn, C1));
            float r2 = __builtin_amdgcn_rcpf(fast_exp2(P2) + 1.0f);
            Q[k] = fmaf(T, r2, Q2);
            P[k] = P2;
        }
    }

    // final scale [1, -1] and unscale by 1/c
    #pragma unroll
    for (int k = 0; k < PPT / 2; ++k) {
        float4 o;
        o.x =  INV_C * Q[2*k];   o.y = -INV_C * P[2*k];
        o.z =  INV_C * Q[2*k+1]; o.w = -INV_C * P[2*k+1];
        out4[base + k] = o;
    }
}

extern "C" void kernel_launch(void* const* d_in, const int* in_sizes, int n_in,
                              void* d_out, int out_size, void* d_ws, size_t ws_size,
                              hipStream_t stream) {
    const float* x      = (const float*)d_in[0];
    const float* act_w  = (const float*)d_in[1];
    const float* bias_b = (const float*)d_in[2];
    const float* lin_w  = (const float*)d_in[3];
    float* out = (float*)d_out;
    float* tab = (float*)d_ws;   // NL*16 floats = 2 KB

    build_tables<<<1, 64, 0, stream>>>(act_w, bias_b, lin_w, tab);

    int npts = in_sizes[0] / 2;                    // 2097152
    int nthreads = npts / PPT;                     // 262144
    int blocks = (nthreads + 255) / 256;           // 1024
    sympnet_main<<<blocks, 256, 0, stream>>>(x, tab, out);
}